// Round 4
// baseline (2808.407 us; speedup 1.0000x reference)
//
#include <hip/hip_runtime.h>
#include <hip/hip_bf16.h>

typedef __attribute__((ext_vector_type(8))) short short8;
typedef __attribute__((ext_vector_type(4))) float floatx4;

#define S_LEN  50
#define BATCH  128
#define DIM    512
#define HID    512
#define G3     1536
#define VOCAB  30000
#define TOKENS 6400
#define NVB    ((VOCAB + 127) / 128)   // 235 v-chunks in decode

__device__ __forceinline__ float bf2f(short u) {
    union { unsigned int i; float f; } c;
    c.i = ((unsigned int)(unsigned short)u) << 16;
    return c.f;
}
__device__ __forceinline__ unsigned short f2bf(float x) {
    __hip_bfloat16 h = __float2bfloat16(x);
    unsigned short u;
    __builtin_memcpy(&u, &h, 2);
    return u;
}

// ---------------- f32 -> bf16 bulk convert (8 elems/thread) ----------------
__global__ void k_cvt_bf16(const float* __restrict__ src,
                           unsigned short* __restrict__ dst, int n8) {
    int g = blockIdx.x * 256 + threadIdx.x;
    if (g >= n8) return;
    const float* s = src + (size_t)g * 8;
    union { short8 v; unsigned short u[8]; } o;
#pragma unroll
    for (int i = 0; i < 8; ++i) o.u[i] = f2bf(s[i]);
    *(short8*)(dst + (size_t)g * 8) = o.v;
}

// ---------------- embedding gather + convert: X[token][512] bf16 ----------------
__global__ void k_gather_x(const float* __restrict__ emb, const int* __restrict__ idx,
                           unsigned short* __restrict__ X) {
    int g = blockIdx.x * 256 + threadIdx.x;   // 8-elem group; total TOKENS*DIM/8
    int token = g >> 6;                       // 64 groups per token
    int chunk = (g & 63) << 3;
    const float* src = emb + (size_t)idx[token] * DIM + chunk;
    union { short8 v; unsigned short u[8]; } o;
#pragma unroll
    for (int i = 0; i < 8; ++i) o.u[i] = f2bf(src[i]);
    *(short8*)(X + (size_t)token * DIM + chunk) = o.v;
}

// ---------------- GI = X @ W_ih^T + b_ih   [6400 x 1536] fp32 ----------------
// NT GEMM, bf16 MFMA 16x16x32. Block: 256 thr (4 waves), tile 64x64, BK=64.
__launch_bounds__(256)
__global__ void k_gemm_gi(const unsigned short* __restrict__ X,
                          const unsigned short* __restrict__ Wih,
                          const float* __restrict__ b_ih,
                          float* __restrict__ GI) {
    __shared__ unsigned short As[64][72];
    __shared__ unsigned short Bs[64][72];
    int m0 = blockIdx.x * 64;
    int n0 = blockIdx.y * 64;
    int t = threadIdx.x;
    int w = t >> 6, lane = t & 63;
    floatx4 zero = {0.f, 0.f, 0.f, 0.f};
    floatx4 acc[4];
#pragma unroll
    for (int i = 0; i < 4; ++i) acc[i] = zero;
    int srow = t >> 2, scol = (t & 3) * 16;
    for (int k0 = 0; k0 < DIM; k0 += 64) {
        *(short8*)&As[srow][scol]     = *(const short8*)(X   + (size_t)(m0 + srow) * DIM + k0 + scol);
        *(short8*)&As[srow][scol + 8] = *(const short8*)(X   + (size_t)(m0 + srow) * DIM + k0 + scol + 8);
        *(short8*)&Bs[srow][scol]     = *(const short8*)(Wih + (size_t)(n0 + srow) * DIM + k0 + scol);
        *(short8*)&Bs[srow][scol + 8] = *(const short8*)(Wih + (size_t)(n0 + srow) * DIM + k0 + scol + 8);
        __syncthreads();
#pragma unroll
        for (int kt = 0; kt < 2; ++kt) {
            short8 a = *(const short8*)&As[w * 16 + (lane & 15)][kt * 32 + (lane >> 4) * 8];
#pragma unroll
            for (int nt = 0; nt < 4; ++nt) {
                short8 b = *(const short8*)&Bs[nt * 16 + (lane & 15)][kt * 32 + (lane >> 4) * 8];
                acc[nt] = __builtin_amdgcn_mfma_f32_16x16x32_bf16(a, b, acc[nt], 0, 0, 0);
            }
        }
        __syncthreads();
    }
#pragma unroll
    for (int nt = 0; nt < 4; ++nt)
#pragma unroll
        for (int r = 0; r < 4; ++r) {
            int row = m0 + w * 16 + (lane >> 4) * 4 + r;
            int col = n0 + nt * 16 + (lane & 15);
            GI[(size_t)row * G3 + col] = acc[nt][r] + b_ih[col];
        }
}

// ---------------- GRU recurrence: 8 blocks x 16 batch rows, 50 steps ----------------
// h state in LDS (fp32 + bf16 copy). Per step: gh = h @ W_hh^T via MFMA (B-frags
// straight from L2-resident W_hh_bf16), then fused gates, write hs (bf16).
__launch_bounds__(512)
__global__ void k_gru(const float* __restrict__ GI,
                      const unsigned short* __restrict__ Whh,
                      const float* __restrict__ b_hh,
                      unsigned short* __restrict__ HS) {
    __shared__ float          hf[16][520];
    __shared__ unsigned short hb[16][520];
    int t = threadIdx.x;
    int w = t >> 6, lane = t & 63;
    int b0 = blockIdx.x * 16;
    for (int i = t; i < 16 * 520; i += 512) ((float*)hf)[i] = 0.f;
    __syncthreads();

    // per-wave W_hh row pointers: wave w owns j-tiles w*4..w*4+3 (times 3 gates)
    const unsigned short* pw[4][3];
#pragma unroll
    for (int i = 0; i < 4; ++i) {
        int j16 = (w * 4 + i) * 16 + (lane & 15);
#pragma unroll
        for (int g = 0; g < 3; ++g)
            pw[i][g] = Whh + (size_t)(g * HID + j16) * DIM + (lane >> 4) * 8;
    }

    for (int s = 0; s < S_LEN; ++s) {
        // fp32 h -> bf16 copy
        for (int i = t; i < 16 * 512; i += 512) {
            int r = i >> 9, c = i & 511;
            hb[r][c] = f2bf(hf[r][c]);
        }
        __syncthreads();

        floatx4 zero = {0.f, 0.f, 0.f, 0.f};
        floatx4 acc[4][3];
#pragma unroll
        for (int i = 0; i < 4; ++i)
#pragma unroll
            for (int g = 0; g < 3; ++g) acc[i][g] = zero;

#pragma unroll 4
        for (int kt = 0; kt < 16; ++kt) {
            short8 a = *(const short8*)&hb[lane & 15][kt * 32 + (lane >> 4) * 8];
#pragma unroll
            for (int i = 0; i < 4; ++i)
#pragma unroll
                for (int g = 0; g < 3; ++g) {
                    short8 b = *(const short8*)(pw[i][g] + kt * 32);
                    acc[i][g] = __builtin_amdgcn_mfma_f32_16x16x32_bf16(a, b, acc[i][g], 0, 0, 0);
                }
        }
        __syncthreads();

        // gates + state update (wave owns j in [w*64, w*64+64))
#pragma unroll
        for (int i = 0; i < 4; ++i) {
            int j = (w * 4 + i) * 16 + (lane & 15);
            float bhr = b_hh[j], bhz = b_hh[j + 512], bhn = b_hh[j + 1024];
#pragma unroll
            for (int r = 0; r < 4; ++r) {
                int bl = (lane >> 4) * 4 + r;
                int tok = s * BATCH + b0 + bl;
                const float* gi = GI + (size_t)tok * G3;
                float ghr = acc[i][0][r] + bhr;
                float ghz = acc[i][1][r] + bhz;
                float ghn = acc[i][2][r] + bhn;
                float rg = 1.f / (1.f + __expf(-(gi[j] + ghr)));
                float zg = 1.f / (1.f + __expf(-(gi[j + 512] + ghz)));
                float ng = tanhf(gi[j + 1024] + rg * ghn);
                float hn = (1.f - zg) * ng + zg * hf[bl][j];
                hf[bl][j] = hn;
                HS[(size_t)tok * HID + j] = f2bf(hn);
            }
        }
        __syncthreads();
    }
}

// ---------------- decode: partial sum(exp(logit)) per (token, v-chunk) ----------------
// Block: 256 thr (4 waves), tile M=64 tokens x N=128 vocab, BK=64.
__launch_bounds__(256)
__global__ void k_decode(const unsigned short* __restrict__ HS,
                         const unsigned short* __restrict__ Wout,
                         const float* __restrict__ b_out,
                         float* __restrict__ partial) {
    __shared__ unsigned short As[64][72];
    __shared__ unsigned short Bs[128][72];
    int m0 = blockIdx.x * 64;
    int nb = blockIdx.y;
    int n0 = nb * 128;
    int t = threadIdx.x, w = t >> 6, lane = t & 63;
    floatx4 zero = {0.f, 0.f, 0.f, 0.f};
    floatx4 acc[8];
#pragma unroll
    for (int i = 0; i < 8; ++i) acc[i] = zero;
    int arow = t >> 2, acol = (t & 3) * 16;
    int brow = t >> 1, bcol = (t & 1) * 32;
    short8 z8 = {0, 0, 0, 0, 0, 0, 0, 0};
    for (int k0 = 0; k0 < DIM; k0 += 64) {
        *(short8*)&As[arow][acol]     = *(const short8*)(HS + (size_t)(m0 + arow) * DIM + k0 + acol);
        *(short8*)&As[arow][acol + 8] = *(const short8*)(HS + (size_t)(m0 + arow) * DIM + k0 + acol + 8);
        int v = n0 + brow;
        if (v < VOCAB) {
            const unsigned short* wp = Wout + (size_t)v * DIM + k0 + bcol;
#pragma unroll
            for (int q = 0; q < 4; ++q)
                *(short8*)&Bs[brow][bcol + q * 8] = *(const short8*)(wp + q * 8);
        } else {
#pragma unroll
            for (int q = 0; q < 4; ++q) *(short8*)&Bs[brow][bcol + q * 8] = z8;
        }
        __syncthreads();
#pragma unroll
        for (int kt = 0; kt < 2; ++kt) {
            short8 a = *(const short8*)&As[w * 16 + (lane & 15)][kt * 32 + (lane >> 4) * 8];
#pragma unroll
            for (int nt = 0; nt < 8; ++nt) {
                short8 b = *(const short8*)&Bs[nt * 16 + (lane & 15)][kt * 32 + (lane >> 4) * 8];
                acc[nt] = __builtin_amdgcn_mfma_f32_16x16x32_bf16(a, b, acc[nt], 0, 0, 0);
            }
        }
        __syncthreads();
    }
    float esum[4] = {0.f, 0.f, 0.f, 0.f};
#pragma unroll
    for (int nt = 0; nt < 8; ++nt) {
        int v = n0 + nt * 16 + (lane & 15);
        bool ok = v < VOCAB;
        float bo = ok ? b_out[v] : 0.f;
#pragma unroll
        for (int r = 0; r < 4; ++r) {
            float logit = acc[nt][r] + bo;
            esum[r] += ok ? __expf(logit) : 0.f;
        }
    }
#pragma unroll
    for (int d = 1; d < 16; d <<= 1)
#pragma unroll
        for (int r = 0; r < 4; ++r) esum[r] += __shfl_xor(esum[r], d, 64);
    if ((lane & 15) == 0) {
#pragma unroll
        for (int r = 0; r < 4; ++r) {
            int tok = m0 + w * 16 + (lane >> 4) * 4 + r;
            partial[(size_t)tok * 256 + nb] = esum[r];
        }
    }
}

// ---------------- fixed-order reduce of partials -> lse ----------------
__global__ void k_reduce_lse(const float* __restrict__ partial, float* __restrict__ lse) {
    int tok = blockIdx.x * 4 + (threadIdx.x >> 6);
    int lane = threadIdx.x & 63;
    float s = 0.f;
    for (int j = lane; j < NVB; j += 64) s += partial[(size_t)tok * 256 + j];
#pragma unroll
    for (int d = 1; d < 64; d <<= 1) s += __shfl_xor(s, d, 64);
    if (lane == 0) lse[tok] = logf(s);
}

// ---------------- target logit: one wave per token ----------------
__global__ void k_tlogit(const unsigned short* __restrict__ HS,
                         const unsigned short* __restrict__ Wout,
                         const float* __restrict__ b_out,
                         const int* __restrict__ target,
                         float* __restrict__ tlg) {
    int tok = blockIdx.x * 4 + (threadIdx.x >> 6);
    int lane = threadIdx.x & 63;
    int tg = target[tok];
    short8 a = *(const short8*)(HS + (size_t)tok * DIM + lane * 8);
    short8 b = *(const short8*)(Wout + (size_t)tg * DIM + lane * 8);
    float s = 0.f;
#pragma unroll
    for (int i = 0; i < 8; ++i) s += bf2f(a[i]) * bf2f(b[i]);
#pragma unroll
    for (int d = 1; d < 64; d <<= 1) s += __shfl_xor(s, d, 64);
    if (lane == 0) tlg[tok] = s + b_out[tg];
}

// ---------------- loss + masked mean ----------------
__global__ void k_finalize(const float* __restrict__ lse, const float* __restrict__ tlg,
                           const int* __restrict__ target, float* __restrict__ out) {
    __shared__ float ssum[256];
    __shared__ float scnt[256];
    int t = threadIdx.x;
    float ls = 0.f, lc = 0.f;
    for (int i = t; i < TOKENS; i += 256) {
        int tg = target[i];
        float loss = (tg != 0) ? (lse[i] - tlg[i]) : 0.f;
        out[i] = loss;
        ls += loss;
        lc += (tg != 0) ? 1.f : 0.f;
    }
    ssum[t] = ls; scnt[t] = lc;
    __syncthreads();
    for (int d = 128; d > 0; d >>= 1) {
        if (t < d) { ssum[t] += ssum[t + d]; scnt[t] += scnt[t + d]; }
        __syncthreads();
    }
    if (t == 0) out[TOKENS] = ssum[0] / fmaxf(scnt[0], 1.f);
}

extern "C" void kernel_launch(void* const* d_in, const int* in_sizes, int n_in,
                              void* d_out, int out_size, void* d_ws, size_t ws_size,
                              hipStream_t stream) {
    const int*   review_input  = (const int*)d_in[2];
    const int*   review_target = (const int*)d_in[3];
    const float* word_emb      = (const float*)d_in[4];
    const float* W_ih          = (const float*)d_in[5];
    const float* W_hh          = (const float*)d_in[6];
    const float* b_ih          = (const float*)d_in[7];
    const float* b_hh          = (const float*)d_in[8];
    const float* W_out         = (const float*)d_in[9];
    const float* b_out         = (const float*)d_in[10];
    float* out = (float*)d_out;

    char* ws = (char*)d_ws;
    size_t off = 0;
    auto alloc = [&](size_t n) { char* p = ws + off; off += (n + 255) & ~(size_t)255; return p; };
    unsigned short* Xb    = (unsigned short*)alloc((size_t)TOKENS * DIM * 2);
    unsigned short* Wihb  = (unsigned short*)alloc((size_t)G3 * DIM * 2);
    unsigned short* Whhb  = (unsigned short*)alloc((size_t)G3 * HID * 2);
    unsigned short* Woutb = (unsigned short*)alloc((size_t)VOCAB * DIM * 2);
    unsigned short* HS    = (unsigned short*)alloc((size_t)TOKENS * HID * 2);
    float* GI      = (float*)alloc((size_t)TOKENS * G3 * 4);
    float* partial = (float*)alloc((size_t)TOKENS * 256 * 4);
    float* lse     = (float*)alloc((size_t)TOKENS * 4);
    float* tlg     = (float*)alloc((size_t)TOKENS * 4);
    (void)ws_size; (void)in_sizes; (void)n_in; (void)out_size;

    // weight conversions + embedding gather
    k_cvt_bf16<<<dim3((G3 * DIM / 8 + 255) / 256), dim3(256), 0, stream>>>(W_ih, Wihb, G3 * DIM / 8);
    k_cvt_bf16<<<dim3((G3 * HID / 8 + 255) / 256), dim3(256), 0, stream>>>(W_hh, Whhb, G3 * HID / 8);
    k_cvt_bf16<<<dim3((VOCAB * DIM / 8 + 255) / 256), dim3(256), 0, stream>>>(W_out, Woutb, VOCAB * DIM / 8);
    k_gather_x<<<dim3(TOKENS * DIM / 8 / 256), dim3(256), 0, stream>>>(word_emb, review_input, Xb);

    // GI = X @ W_ih^T + b_ih
    k_gemm_gi<<<dim3(TOKENS / 64, G3 / 64), dim3(256), 0, stream>>>(Xb, Wihb, b_ih, GI);

    // GRU recurrence -> HS (bf16)
    k_gru<<<dim3(BATCH / 16), dim3(512), 0, stream>>>(GI, Whhb, b_hh, HS);

    // decode: partial exp-sums, reduce to lse, target logits, final loss
    k_decode<<<dim3(TOKENS / 64, NVB), dim3(256), 0, stream>>>(HS, Woutb, b_out, partial);
    k_reduce_lse<<<dim3(TOKENS / 4), dim3(256), 0, stream>>>(partial, lse);
    k_tlogit<<<dim3(TOKENS / 4), dim3(256), 0, stream>>>(HS, Woutb, b_out, review_target, tlg);
    k_finalize<<<dim3(1), dim3(256), 0, stream>>>(lse, tlg, review_target, out);
}

// Round 5
// 714.458 us; speedup vs baseline: 3.9308x; 3.9308x over previous
//
#include <hip/hip_runtime.h>
#include <hip/hip_bf16.h>

typedef __attribute__((ext_vector_type(8))) short short8;
typedef __attribute__((ext_vector_type(4))) float floatx4;

#define S_LEN  50
#define BATCH  128
#define DIM    512
#define HID    512
#define G3     1536
#define VOCAB  30000
#define TOKENS 6400
#define NVB    ((VOCAB + 127) / 128)   // 235 v-chunks in decode

__device__ __forceinline__ float bf2f(short u) {
    union { unsigned int i; float f; } c;
    c.i = ((unsigned int)(unsigned short)u) << 16;
    return c.f;
}
__device__ __forceinline__ unsigned short f2bf(float x) {
    __hip_bfloat16 h = __float2bfloat16(x);
    unsigned short u;
    __builtin_memcpy(&u, &h, 2);
    return u;
}

// ---------------- f32 -> bf16 bulk convert (8 elems/thread) ----------------
__global__ void k_cvt_bf16(const float* __restrict__ src,
                           unsigned short* __restrict__ dst, int n8) {
    int g = blockIdx.x * 256 + threadIdx.x;
    if (g >= n8) return;
    const float* s = src + (size_t)g * 8;
    union { short8 v; unsigned short u[8]; } o;
#pragma unroll
    for (int i = 0; i < 8; ++i) o.u[i] = f2bf(s[i]);
    *(short8*)(dst + (size_t)g * 8) = o.v;
}

// ---------------- embedding gather + convert: X[token][512] bf16 ----------------
__global__ void k_gather_x(const float* __restrict__ emb, const int* __restrict__ idx,
                           unsigned short* __restrict__ X) {
    int g = blockIdx.x * 256 + threadIdx.x;   // 8-elem group; total TOKENS*DIM/8
    int token = g >> 6;                       // 64 groups per token
    int chunk = (g & 63) << 3;
    const float* src = emb + (size_t)idx[token] * DIM + chunk;
    union { short8 v; unsigned short u[8]; } o;
#pragma unroll
    for (int i = 0; i < 8; ++i) o.u[i] = f2bf(src[i]);
    *(short8*)(X + (size_t)token * DIM + chunk) = o.v;
}

// ---------------- GI = X @ W_ih^T + b_ih   [6400 x 1536] fp32 ----------------
// NT GEMM, bf16 MFMA 16x16x32. Block: 256 thr (4 waves), tile 64x64, BK=64.
__launch_bounds__(256)
__global__ void k_gemm_gi(const unsigned short* __restrict__ X,
                          const unsigned short* __restrict__ Wih,
                          const float* __restrict__ b_ih,
                          float* __restrict__ GI) {
    __shared__ unsigned short As[64][72];
    __shared__ unsigned short Bs[64][72];
    int m0 = blockIdx.x * 64;
    int n0 = blockIdx.y * 64;
    int t = threadIdx.x;
    int w = t >> 6, lane = t & 63;
    floatx4 zero = {0.f, 0.f, 0.f, 0.f};
    floatx4 acc[4];
#pragma unroll
    for (int i = 0; i < 4; ++i) acc[i] = zero;
    int srow = t >> 2, scol = (t & 3) * 16;
    for (int k0 = 0; k0 < DIM; k0 += 64) {
        *(short8*)&As[srow][scol]     = *(const short8*)(X   + (size_t)(m0 + srow) * DIM + k0 + scol);
        *(short8*)&As[srow][scol + 8] = *(const short8*)(X   + (size_t)(m0 + srow) * DIM + k0 + scol + 8);
        *(short8*)&Bs[srow][scol]     = *(const short8*)(Wih + (size_t)(n0 + srow) * DIM + k0 + scol);
        *(short8*)&Bs[srow][scol + 8] = *(const short8*)(Wih + (size_t)(n0 + srow) * DIM + k0 + scol + 8);
        __syncthreads();
#pragma unroll
        for (int kt = 0; kt < 2; ++kt) {
            short8 a = *(const short8*)&As[w * 16 + (lane & 15)][kt * 32 + (lane >> 4) * 8];
#pragma unroll
            for (int nt = 0; nt < 4; ++nt) {
                short8 b = *(const short8*)&Bs[nt * 16 + (lane & 15)][kt * 32 + (lane >> 4) * 8];
                acc[nt] = __builtin_amdgcn_mfma_f32_16x16x32_bf16(a, b, acc[nt], 0, 0, 0);
            }
        }
        __syncthreads();
    }
#pragma unroll
    for (int nt = 0; nt < 4; ++nt)
#pragma unroll
        for (int r = 0; r < 4; ++r) {
            int row = m0 + w * 16 + (lane >> 4) * 4 + r;
            int col = n0 + nt * 16 + (lane & 15);
            GI[(size_t)row * G3 + col] = acc[nt][r] + b_ih[col];
        }
}

// ---------------- GRU single step: h_t = GRUCell(h_{t-1}, GI_t) ----------------
// 128 blocks x 128 thr (2 waves). Block = (batch group bg of 16 rows) x
// (hidden slice hs of 32 units). Wave w owns hidden tile hs*32 + w*16, all 3
// gates. A (h_{t-1} bf16) from hin = HS rows of step s-1 (or zeros at s=0);
// h_new written to hf (fp32 carry) + hout = HS rows of step s. No intra-step
// hazards: hin/hout are disjoint global rows, hf rectangle-exclusive per block.
__launch_bounds__(128)
__global__ void k_gru_step(const float* __restrict__ GI,
                           const unsigned short* __restrict__ Whh,
                           const float* __restrict__ b_hh,
                           float* __restrict__ hf,
                           const unsigned short* __restrict__ hin,
                           unsigned short* __restrict__ hout,
                           int s) {
    int t = threadIdx.x;
    int w = t >> 6, lane = t & 63;
    int bg = blockIdx.x & 7;      // batch group
    int hs = blockIdx.x >> 3;     // hidden slice (16 slices of 32)
    int jc = hs * 32 + w * 16 + (lane & 15);   // hidden unit this lane covers (N index)

    const unsigned short* pa  = hin + (size_t)(bg * 16 + (lane & 15)) * HID + (lane >> 4) * 8;
    const unsigned short* pb0 = Whh + (size_t)(0 * HID + jc) * DIM + (lane >> 4) * 8;
    const unsigned short* pb1 = Whh + (size_t)(1 * HID + jc) * DIM + (lane >> 4) * 8;
    const unsigned short* pb2 = Whh + (size_t)(2 * HID + jc) * DIM + (lane >> 4) * 8;

    floatx4 acc0 = {0.f, 0.f, 0.f, 0.f};
    floatx4 acc1 = {0.f, 0.f, 0.f, 0.f};
    floatx4 acc2 = {0.f, 0.f, 0.f, 0.f};
#pragma unroll
    for (int kt = 0; kt < 16; ++kt) {
        short8 a = *(const short8*)(pa + kt * 32);
        acc0 = __builtin_amdgcn_mfma_f32_16x16x32_bf16(a, *(const short8*)(pb0 + kt * 32), acc0, 0, 0, 0);
        acc1 = __builtin_amdgcn_mfma_f32_16x16x32_bf16(a, *(const short8*)(pb1 + kt * 32), acc1, 0, 0, 0);
        acc2 = __builtin_amdgcn_mfma_f32_16x16x32_bf16(a, *(const short8*)(pb2 + kt * 32), acc2, 0, 0, 0);
    }
    float bhr = b_hh[jc], bhz = b_hh[jc + 512], bhn = b_hh[jc + 1024];
#pragma unroll
    for (int r = 0; r < 4; ++r) {
        int brow = bg * 16 + (lane >> 4) * 4 + r;   // batch row (M index)
        int tok = s * BATCH + brow;
        const float* gi = GI + (size_t)tok * G3;
        float rg = 1.f / (1.f + __expf(-(gi[jc] + acc0[r] + bhr)));
        float zg = 1.f / (1.f + __expf(-(gi[jc + 512] + acc1[r] + bhz)));
        float ng = tanhf(gi[jc + 1024] + rg * (acc2[r] + bhn));
        size_t hidx = (size_t)brow * HID + jc;
        float hn = (1.f - zg) * ng + zg * hf[hidx];
        hf[hidx] = hn;
        hout[hidx] = f2bf(hn);
    }
}

// ---------------- decode: partial sum(exp(logit)) per (token, v-chunk) ----------------
// Block: 256 thr (4 waves), tile M=64 tokens x N=128 vocab, BK=64.
__launch_bounds__(256)
__global__ void k_decode(const unsigned short* __restrict__ HS,
                         const unsigned short* __restrict__ Wout,
                         const float* __restrict__ b_out,
                         float* __restrict__ partial) {
    __shared__ unsigned short As[64][72];
    __shared__ unsigned short Bs[128][72];
    int m0 = blockIdx.x * 64;
    int nb = blockIdx.y;
    int n0 = nb * 128;
    int t = threadIdx.x, w = t >> 6, lane = t & 63;
    floatx4 zero = {0.f, 0.f, 0.f, 0.f};
    floatx4 acc[8];
#pragma unroll
    for (int i = 0; i < 8; ++i) acc[i] = zero;
    int arow = t >> 2, acol = (t & 3) * 16;
    int brow = t >> 1, bcol = (t & 1) * 32;
    short8 z8 = {0, 0, 0, 0, 0, 0, 0, 0};
    for (int k0 = 0; k0 < DIM; k0 += 64) {
        *(short8*)&As[arow][acol]     = *(const short8*)(HS + (size_t)(m0 + arow) * DIM + k0 + acol);
        *(short8*)&As[arow][acol + 8] = *(const short8*)(HS + (size_t)(m0 + arow) * DIM + k0 + acol + 8);
        int v = n0 + brow;
        if (v < VOCAB) {
            const unsigned short* wp = Wout + (size_t)v * DIM + k0 + bcol;
#pragma unroll
            for (int q = 0; q < 4; ++q)
                *(short8*)&Bs[brow][bcol + q * 8] = *(const short8*)(wp + q * 8);
        } else {
#pragma unroll
            for (int q = 0; q < 4; ++q) *(short8*)&Bs[brow][bcol + q * 8] = z8;
        }
        __syncthreads();
#pragma unroll
        for (int kt = 0; kt < 2; ++kt) {
            short8 a = *(const short8*)&As[w * 16 + (lane & 15)][kt * 32 + (lane >> 4) * 8];
#pragma unroll
            for (int nt = 0; nt < 8; ++nt) {
                short8 b = *(const short8*)&Bs[nt * 16 + (lane & 15)][kt * 32 + (lane >> 4) * 8];
                acc[nt] = __builtin_amdgcn_mfma_f32_16x16x32_bf16(a, b, acc[nt], 0, 0, 0);
            }
        }
        __syncthreads();
    }
    float esum[4] = {0.f, 0.f, 0.f, 0.f};
#pragma unroll
    for (int nt = 0; nt < 8; ++nt) {
        int v = n0 + nt * 16 + (lane & 15);
        bool ok = v < VOCAB;
        float bo = ok ? b_out[v] : 0.f;
#pragma unroll
        for (int r = 0; r < 4; ++r) {
            float logit = acc[nt][r] + bo;
            esum[r] += ok ? __expf(logit) : 0.f;
        }
    }
#pragma unroll
    for (int d = 1; d < 16; d <<= 1)
#pragma unroll
        for (int r = 0; r < 4; ++r) esum[r] += __shfl_xor(esum[r], d, 64);
    if ((lane & 15) == 0) {
#pragma unroll
        for (int r = 0; r < 4; ++r) {
            int tok = m0 + w * 16 + (lane >> 4) * 4 + r;
            partial[(size_t)tok * 256 + nb] = esum[r];
        }
    }
}

// ---------------- fixed-order reduce of partials -> lse ----------------
__global__ void k_reduce_lse(const float* __restrict__ partial, float* __restrict__ lse) {
    int tok = blockIdx.x * 4 + (threadIdx.x >> 6);
    int lane = threadIdx.x & 63;
    float s = 0.f;
    for (int j = lane; j < NVB; j += 64) s += partial[(size_t)tok * 256 + j];
#pragma unroll
    for (int d = 1; d < 64; d <<= 1) s += __shfl_xor(s, d, 64);
    if (lane == 0) lse[tok] = logf(s);
}

// ---------------- target logit: one wave per token ----------------
__global__ void k_tlogit(const unsigned short* __restrict__ HS,
                         const unsigned short* __restrict__ Wout,
                         const float* __restrict__ b_out,
                         const int* __restrict__ target,
                         float* __restrict__ tlg) {
    int tok = blockIdx.x * 4 + (threadIdx.x >> 6);
    int lane = threadIdx.x & 63;
    int tg = target[tok];
    short8 a = *(const short8*)(HS + (size_t)tok * DIM + lane * 8);
    short8 b = *(const short8*)(Wout + (size_t)tg * DIM + lane * 8);
    float s = 0.f;
#pragma unroll
    for (int i = 0; i < 8; ++i) s += bf2f(a[i]) * bf2f(b[i]);
#pragma unroll
    for (int d = 1; d < 64; d <<= 1) s += __shfl_xor(s, d, 64);
    if (lane == 0) tlg[tok] = s + b_out[tg];
}

// ---------------- loss + masked mean ----------------
__global__ void k_finalize(const float* __restrict__ lse, const float* __restrict__ tlg,
                           const int* __restrict__ target, float* __restrict__ out) {
    __shared__ float ssum[256];
    __shared__ float scnt[256];
    int t = threadIdx.x;
    float ls = 0.f, lc = 0.f;
    for (int i = t; i < TOKENS; i += 256) {
        int tg = target[i];
        float loss = (tg != 0) ? (lse[i] - tlg[i]) : 0.f;
        out[i] = loss;
        ls += loss;
        lc += (tg != 0) ? 1.f : 0.f;
    }
    ssum[t] = ls; scnt[t] = lc;
    __syncthreads();
    for (int d = 128; d > 0; d >>= 1) {
        if (t < d) { ssum[t] += ssum[t + d]; scnt[t] += scnt[t + d]; }
        __syncthreads();
    }
    if (t == 0) out[TOKENS] = ssum[0] / fmaxf(scnt[0], 1.f);
}

extern "C" void kernel_launch(void* const* d_in, const int* in_sizes, int n_in,
                              void* d_out, int out_size, void* d_ws, size_t ws_size,
                              hipStream_t stream) {
    const int*   review_input  = (const int*)d_in[2];
    const int*   review_target = (const int*)d_in[3];
    const float* word_emb      = (const float*)d_in[4];
    const float* W_ih          = (const float*)d_in[5];
    const float* W_hh          = (const float*)d_in[6];
    const float* b_ih          = (const float*)d_in[7];
    const float* b_hh          = (const float*)d_in[8];
    const float* W_out         = (const float*)d_in[9];
    const float* b_out         = (const float*)d_in[10];
    float* out = (float*)d_out;

    char* ws = (char*)d_ws;
    size_t off = 0;
    auto alloc = [&](size_t n) { char* p = ws + off; off += (n + 255) & ~(size_t)255; return p; };
    unsigned short* Xb    = (unsigned short*)alloc((size_t)TOKENS * DIM * 2);
    unsigned short* Wihb  = (unsigned short*)alloc((size_t)G3 * DIM * 2);
    unsigned short* Whhb  = (unsigned short*)alloc((size_t)G3 * HID * 2);
    unsigned short* Woutb = (unsigned short*)alloc((size_t)VOCAB * DIM * 2);
    unsigned short* HS    = (unsigned short*)alloc((size_t)TOKENS * HID * 2);
    unsigned short* hzero = (unsigned short*)alloc((size_t)BATCH * HID * 2);
    float* hf      = (float*)alloc((size_t)BATCH * HID * 4);
    float* GI      = (float*)alloc((size_t)TOKENS * G3 * 4);
    float* partial = (float*)alloc((size_t)TOKENS * 256 * 4);
    float* lse     = (float*)alloc((size_t)TOKENS * 4);
    float* tlg     = (float*)alloc((size_t)TOKENS * 4);
    (void)ws_size; (void)in_sizes; (void)n_in; (void)out_size;

    // weight conversions + embedding gather
    k_cvt_bf16<<<dim3((G3 * DIM / 8 + 255) / 256), dim3(256), 0, stream>>>(W_ih, Wihb, G3 * DIM / 8);
    k_cvt_bf16<<<dim3((G3 * HID / 8 + 255) / 256), dim3(256), 0, stream>>>(W_hh, Whhb, G3 * HID / 8);
    k_cvt_bf16<<<dim3((VOCAB * DIM / 8 + 255) / 256), dim3(256), 0, stream>>>(W_out, Woutb, VOCAB * DIM / 8);
    k_gather_x<<<dim3(TOKENS * DIM / 8 / 256), dim3(256), 0, stream>>>(word_emb, review_input, Xb);

    // GI = X @ W_ih^T + b_ih
    k_gemm_gi<<<dim3(TOKENS / 64, G3 / 64), dim3(256), 0, stream>>>(Xb, Wihb, b_ih, GI);

    // GRU recurrence: 50 per-step kernels; h carried in hf (fp32) and HS rows (bf16)
    hipMemsetAsync(hf, 0, (size_t)BATCH * HID * 4, stream);
    hipMemsetAsync(hzero, 0, (size_t)BATCH * HID * 2, stream);
    for (int s = 0; s < S_LEN; ++s) {
        const unsigned short* hin = s ? (HS + (size_t)(s - 1) * BATCH * HID) : hzero;
        unsigned short* hout = HS + (size_t)s * BATCH * HID;
        k_gru_step<<<dim3(128), dim3(128), 0, stream>>>(GI, Whhb, b_hh, hf, hin, hout, s);
    }

    // decode: partial exp-sums, reduce to lse, target logits, final loss
    k_decode<<<dim3(TOKENS / 64, NVB), dim3(256), 0, stream>>>(HS, Woutb, b_out, partial);
    k_reduce_lse<<<dim3(TOKENS / 4), dim3(256), 0, stream>>>(partial, lse);
    k_tlogit<<<dim3(TOKENS / 4), dim3(256), 0, stream>>>(HS, Woutb, b_out, review_target, tlg);
    k_finalize<<<dim3(1), dim3(256), 0, stream>>>(lse, tlg, review_target, out);
}